// Round 15
// baseline (2872.915 us; speedup 1.0000x reference)
//
#include <hip/hip_runtime.h>
#include <cstdint>
#include <cstddef>

// Problem constants (reference: BS,SEQ,VOCAB,EMS,NHID,ML = 32,512,5000,256,512,16)
#define BS     32
#define SEQ    512
#define VOCAB  5000
#define EMS    256
#define NHID   512
#define GH     2048        // 4*NHID gate rows
#define SLICE  16
#define VPAD   5120        // VOCAB padded to 128
#define NTILE  ((BS*SEQ/128) * (VPAD/128))   // 128 x 40 = 5120 decode tiles

// ---- workspace layout (bytes); ~55.7 MB ----
#define WS_BIAS  0                                 // f32[2048]  (b_ih+b_hh)
#define WS_WIH   (WS_BIAS + GH*4)                  // bf16[2048][256]
#define WS_WHH   (WS_WIH + GH*EMS*2)               // bf16[2048][512]
#define WS_WDH   (WS_WHH + GH*NHID*2)              // bf16[5120][512] W_dec hi
#define WS_WDL   (WS_WDH + VPAD*NHID*2)            // bf16[5120][512] W_dec lo
#define WS_X     (WS_WDL + VPAD*NHID*2)            // bf16[512][32][256] emb gather (t-major)
#define WS_HHI   (WS_X + SEQ*BS*EMS*2)             // bf16[32*512][512] h hi (b-major rows b*512+t)
#define WS_HLO   (WS_HHI + BS*SEQ*NHID*2)          // bf16[32*512][512] h lo (b-major)
#define WS_TAG   (WS_HLO + BS*SEQ*NHID*2)          // u64[2 parity][2 half][4096] tagged h
#define WS_END   (WS_TAG + 2*8192*8)

typedef float f32x4 __attribute__((ext_vector_type(4)));
typedef __bf16 bf16x8 __attribute__((ext_vector_type(8)));

static __device__ __forceinline__ uint16_t f2bf(float x) {
  uint32_t u = __builtin_bit_cast(uint32_t, x);
  u += 0x7FFFu + ((u >> 16) & 1u);        // RNE (inputs finite)
  return (uint16_t)(u >> 16);
}
static __device__ __forceinline__ float bf2f(uint16_t b) {
  return __builtin_bit_cast(float, (uint32_t)b << 16);
}
static __device__ __forceinline__ float sigf(float x) { return 1.0f / (1.0f + __expf(-x)); }
static __device__ __forceinline__ float tanhf_fast(float x) {
  return 1.0f - 2.0f / (__expf(2.0f * x) + 1.0f);
}
static __device__ __forceinline__ f32x4 mfma16(uint4 a, uint4 b, f32x4 c) {
  return __builtin_amdgcn_mfma_f32_16x16x32_bf16(
      __builtin_bit_cast(bf16x8, a), __builtin_bit_cast(bf16x8, b), c, 0, 0, 0);
}
// async global->LDS, 16B/lane; LDS dest = wave-uniform base + lane*16 (m104)
static __device__ __forceinline__ void glds16(const void* g, void* l) {
  __builtin_amdgcn_global_load_lds((__attribute__((address_space(1))) void*)g,
                                   (__attribute__((address_space(3))) void*)l,
                                   16, 0, 0);
}

// ---------------- prep: bf16 casts, emb gather, W_dec hi/lo split, bias, tagged h0 ----------------
__global__ __launch_bounds__(256) void prep_kernel(
    const int* __restrict__ inputs, const float* __restrict__ h0,
    const float* __restrict__ emb, const float* __restrict__ Wih,
    const float* __restrict__ Whh, const float* __restrict__ bih,
    const float* __restrict__ bhh, const float* __restrict__ Wd,
    char* __restrict__ ws) {
  int gid = blockIdx.x * 256 + threadIdx.x;
  int gsz = gridDim.x * 256;
  uint16_t* wX  = (uint16_t*)(ws + WS_X);
  uint16_t* wIH = (uint16_t*)(ws + WS_WIH);
  uint16_t* wHH = (uint16_t*)(ws + WS_WHH);
  uint16_t* wDH = (uint16_t*)(ws + WS_WDH);
  uint16_t* wDL = (uint16_t*)(ws + WS_WDL);
  float*    bias = (float*)(ws + WS_BIAS);
  unsigned long long* Tg = (unsigned long long*)(ws + WS_TAG);
  // X[t][b][e] = bf16(emb[inputs[b][t]][e]);  i = t*8192 + b*256 + e
  for (int i = gid; i < SEQ*BS*EMS; i += gsz) {
    int e = i & (EMS-1), b = (i >> 8) & (BS-1), t = i >> 13;
    wX[i] = f2bf(emb[(size_t)inputs[b*SEQ + t] * EMS + e]);
  }
  for (int i = gid; i < GH*EMS; i += gsz)  wIH[i] = f2bf(Wih[i]);
  for (int i = gid; i < GH*NHID; i += gsz) wHH[i] = f2bf(Whh[i]);
  for (int i = gid; i < VPAD*NHID; i += gsz) {   // hi/lo split; pad rows >= VOCAB with 0
    int row = i >> 9;
    uint16_t hi = 0, lo = 0;
    if (row < VOCAB) {
      float x = Wd[i];
      hi = f2bf(x);
      lo = f2bf(x - bf2f(hi));
    }
    wDH[i] = hi; wDL[i] = lo;
  }
  for (int i = gid; i < GH; i += gsz) bias[i] = bih[i] + bhh[i];
  // tagged h0, per-half units: u = m*4096 + D*16 + b'  (D = dim-pair 0..255, b' 0..15)
  // parity 0 tag 0; parity 1 sentinel. MUST fully rewrite both each launch (graph replay).
  for (int u = gid; u < 8192; u += gsz) {
    int mm = u >> 12, n = u & 4095;
    int D = n >> 4, bp = n & 15;
    int b = mm*16 + bp;
    uint32_t pay = (uint32_t)f2bf(h0[b*NHID + 2*D]) |
                   ((uint32_t)f2bf(h0[b*NHID + 2*D + 1]) << 16);
    Tg[u] = (unsigned long long)pay;          // parity 0: tag 0 in high bits
    Tg[8192 + u] = 0xFFFFFFFF00000000ull;     // parity 1: sentinel
  }
}

// ---------------- generic 128x128 MFMA GEMM (m97-style) — used for Gin only ----------------
template <int KSTEPS, int NPASS>
__global__ __launch_bounds__(256) void gemm_kernel(
    const uint16_t* __restrict__ A0, const uint16_t* __restrict__ B0,
    const float* __restrict__ bias, float* __restrict__ out,
    int Nvalid, int ldout) {
  constexpr int K = KSTEPS * 32;
  constexpr int TOT = KSTEPS * NPASS;
  __shared__ __align__(16) char lds[4][8192];
  const int tid = threadIdx.x;
  const int lane = tid & 63, w = tid >> 6;
  const int m0 = blockIdx.y * 128, n0 = blockIdx.x * 128;
  const int wbase = (tid & ~63);

  auto stage = [&](int buf, int s) {
    const int kk = s % KSTEPS;
    char* dA = &lds[buf*2][0];
    char* dB = &lds[buf*2+1][0];
#pragma unroll
    for (int c = 0; c < 2; ++c) {
      int idx = c*256 + tid;
      int row = idx >> 2, col = (idx & 3) * 8;
      glds16(A0 + (size_t)(m0 + row) * K + kk*32 + col, dA + (c*256 + wbase)*16);
      glds16(B0 + (size_t)(n0 + row) * K + kk*32 + col, dB + (c*256 + wbase)*16);
    }
  };

  const f32x4 zero = {0.f, 0.f, 0.f, 0.f};
  f32x4 acc[4][4];
#pragma unroll
  for (int i = 0; i < 4; ++i)
#pragma unroll
    for (int j = 0; j < 4; ++j) acc[i][j] = zero;

  const int mq = (w >> 1) * 64, nq = (w & 1) * 64;
  stage(0, 0);
  for (int s = 0; s < TOT; ++s) {
    __syncthreads();
    if (s + 1 < TOT) stage((s + 1) & 1, s + 1);
    const char* cA = &lds[(s & 1)*2][0];
    const char* cB = &lds[(s & 1)*2+1][0];
    uint4 a[4], b[4];
#pragma unroll
    for (int i = 0; i < 4; ++i) {
      a[i] = *(const uint4*)(cA + (mq + i*16 + (lane & 15))*64 + (lane >> 4)*16);
      b[i] = *(const uint4*)(cB + (nq + i*16 + (lane & 15))*64 + (lane >> 4)*16);
    }
#pragma unroll
    for (int i = 0; i < 4; ++i)
#pragma unroll
      for (int j = 0; j < 4; ++j) acc[i][j] = mfma16(a[i], b[j], acc[i][j]);
  }
#pragma unroll
  for (int j = 0; j < 4; ++j) {
    int V = n0 + nq + j*16 + (lane & 15);
    if (V >= Nvalid) continue;
    float bv = bias[V];
#pragma unroll
    for (int i = 0; i < 4; ++i) {
      int Rb = m0 + mq + i*16 + (lane >> 4)*4;
#pragma unroll
      for (int r = 0; r < 4; ++r)
        out[(size_t)(Rb + r) * ldout + V] = acc[i][j][r] + bv;
    }
  }
}

// ---------------- LSTM scan: 64 single-wave WGs, ZERO barriers ----------------
// WG (s,m): 16 batches (half m) x 16 dims (slice s), ALL 4 gates. Lane-local gate combine
// (all 4 gate accs in-lane), wave-local h staging, two independent 32-WG sync groups
// (batch halves) with R13's proven u64-tagged parity-dbuf protocol + full-reissue retry.
__global__ __launch_bounds__(64, 1) void scan_kernel(
    const float* __restrict__ Gin, char* __restrict__ ws,
    const float* __restrict__ c0, float* __restrict__ outT) {
  __shared__ __align__(16) char sW[64*1024];   // W_hh 64 rows (4 gates x 16 dims) x 512, swz
  __shared__ __align__(16) char sH[16*1024];   // h [16 local batches][512], swz
  const uint16_t* wHH = (const uint16_t*)(ws + WS_WHH);
  unsigned long long* Tg = (unsigned long long*)(ws + WS_TAG);
  uint16_t* Hhi = (uint16_t*)(ws + WS_HHI);
  uint16_t* Hlo = (uint16_t*)(ws + WS_HLO);
  const int lane = threadIdx.x;                // single wave
  const int s = (int)blockIdx.x & 31, m = (int)blockIdx.x >> 5;
  // stage W slice once: LDS row = g*16+dl <-> W_hh row g*512 + s*16 + dl
  for (int c = lane; c < 4096; c += 64) {
    int row = c >> 6;
    int kb = (c & 63) * 16;
    int g = row >> 4, dl = row & 15;
    uint4 v = *(const uint4*)(wHH + (size_t)(g*NHID + s*SLICE + dl) * NHID + kb/2);
    *(uint4*)(sW + row*1024 + (kb ^ ((row & 7) << 4))) = v;
  }
  const int il = lane & 15, kq = lane >> 4;
  const int d = s*16 + il;                     // my output dim
  const int bbase = m*16 + kq*4;               // my 4 batches = bbase..bbase+3
  float cst[4];
#pragma unroll
  for (int r = 0; r < 4; ++r) cst[r] = c0[(bbase + r)*NHID + d];
  float ga[16], gb[16];                        // Gin seeds [gate*4+r], dbl-buffered
#pragma unroll
  for (int g = 0; g < 4; ++g)
#pragma unroll
    for (int r = 0; r < 4; ++r)
      ga[g*4+r] = Gin[(size_t)(bbase + r)*GH + g*NHID + d];
  // strip constants
  const int b0r = (2*lane) & 15, b1r = b0r + 1;
  char* sr0 = sH + b0r*1024;
  char* sr1 = sH + b1r*1024;
  const int sw0 = (b0r & 7) << 4, sw1 = (b1r & 7) << 4;

  for (int t = 0; t < SEQ; ++t) {
    // Gin(t+1) prefetch (plain; drained by the poll's vmcnt(0))
    if (t + 1 < SEQ) {
      const float* gr = Gin + (size_t)(t+1)*(BS*GH) + d;
#pragma unroll
      for (int g = 0; g < 4; ++g)
#pragma unroll
        for (int r = 0; r < 4; ++r)
          gb[g*4+r] = gr[(size_t)(bbase + r)*GH + g*NHID];
    }
    // poll-stage my half's h(t): 32 coalesced dwordx4 (wave reads full 32KB span),
    // validate 64 tags in-register, full-reissue retry, strip payloads wave-locally.
    {
      const char* tb = (const char*)(Tg + (size_t)(t & 1)*8192 + (size_t)m*4096) + lane*16;
      const uint32_t tg = (uint32_t)t;
      uint4 q0,q1,q2,q3,q4,q5,q6,q7,q8,q9,q10,q11,q12,q13,q14,q15;
      uint4 q16,q17,q18,q19,q20,q21,q22,q23,q24,q25,q26,q27,q28,q29,q30,q31;
      uint32_t tries = 0;
      for (;;) {
#define PQ(QJ, J) asm volatile("global_load_dwordx4 %0, %1, off sc0 sc1" \
                               : "=v"(QJ) : "v"(tb + (J)*1024));
        PQ(q0,0) PQ(q1,1) PQ(q2,2) PQ(q3,3) PQ(q4,4) PQ(q5,5) PQ(q6,6) PQ(q7,7)
        PQ(q8,8) PQ(q9,9) PQ(q10,10) PQ(q11,11) PQ(q12,12) PQ(q13,13) PQ(q14,14) PQ(q15,15)
        PQ(q16,16) PQ(q17,17) PQ(q18,18) PQ(q19,19) PQ(q20,20) PQ(q21,21) PQ(q22,22) PQ(q23,23)
        PQ(q24,24) PQ(q25,25) PQ(q26,26) PQ(q27,27) PQ(q28,28) PQ(q29,29) PQ(q30,30) PQ(q31,31)
#undef PQ
        asm volatile("s_waitcnt vmcnt(0)" ::: "memory");
        __builtin_amdgcn_sched_barrier(0);
        uint32_t bad =
          (q0.y^tg)|(q0.w^tg)|(q1.y^tg)|(q1.w^tg)|(q2.y^tg)|(q2.w^tg)|(q3.y^tg)|(q3.w^tg)|
          (q4.y^tg)|(q4.w^tg)|(q5.y^tg)|(q5.w^tg)|(q6.y^tg)|(q6.w^tg)|(q7.y^tg)|(q7.w^tg)|
          (q8.y^tg)|(q8.w^tg)|(q9.y^tg)|(q9.w^tg)|(q10.y^tg)|(q10.w^tg)|(q11.y^tg)|(q11.w^tg)|
          (q12.y^tg)|(q12.w^tg)|(q13.y^tg)|(q13.w^tg)|(q14.y^tg)|(q14.w^tg)|(q15.y^tg)|(q15.w^tg)|
          (q16.y^tg)|(q16.w^tg)|(q17.y^tg)|(q17.w^tg)|(q18.y^tg)|(q18.w^tg)|(q19.y^tg)|(q19.w^tg)|
          (q20.y^tg)|(q20.w^tg)|(q21.y^tg)|(q21.w^tg)|(q22.y^tg)|(q22.w^tg)|(q23.y^tg)|(q23.w^tg)|
          (q24.y^tg)|(q24.w^tg)|(q25.y^tg)|(q25.w^tg)|(q26.y^tg)|(q26.w^tg)|(q27.y^tg)|(q27.w^tg)|
          (q28.y^tg)|(q28.w^tg)|(q29.y^tg)|(q29.w^tg)|(q30.y^tg)|(q30.w^tg)|(q31.y^tg)|(q31.w^tg);
        if (!__any((int)(bad != 0u))) break;
        if (++tries > (1u << 14)) break;   // safety: wrong-result beats 600s timeout
      }
      // strip: load J holds dim-pair D=J*8+(lane>>3) for batches b0r,b1r
#define STW(QJ, J) { int cb = ((J)*8 + (lane >> 3)) * 4; \
      *(uint32_t*)(sr0 + (cb ^ sw0)) = (QJ).x; \
      *(uint32_t*)(sr1 + (cb ^ sw1)) = (QJ).z; }
      STW(q0,0) STW(q1,1) STW(q2,2) STW(q3,3) STW(q4,4) STW(q5,5) STW(q6,6) STW(q7,7)
      STW(q8,8) STW(q9,9) STW(q10,10) STW(q11,11) STW(q12,12) STW(q13,13) STW(q14,14) STW(q15,15)
      STW(q16,16) STW(q17,17) STW(q18,18) STW(q19,19) STW(q20,20) STW(q21,21) STW(q22,22) STW(q23,23)
      STW(q24,24) STW(q25,25) STW(q26,26) STW(q27,27) STW(q28,28) STW(q29,29) STW(q30,30) STW(q31,31)
#undef STW
    }
    // 4-gate MFMA (wave-local; compiler inserts lgkmcnt between ds_write/ds_read)
    f32x4 a0, a1, a2, a3;
#pragma unroll
    for (int r = 0; r < 4; ++r) {
      a0[r] = ga[0*4+r]; a1[r] = ga[1*4+r]; a2[r] = ga[2*4+r]; a3[r] = ga[3*4+r];
    }
#pragma unroll
    for (int kt = 0; kt < 16; ++kt) {
      int kb = (kt*64 + kq*16) ^ ((il & 7) << 4);
      uint4 av  = *(const uint4*)(sH + il*1024 + kb);
      uint4 bv0 = *(const uint4*)(sW + (0*16 + il)*1024 + kb);
      uint4 bv1 = *(const uint4*)(sW + (1*16 + il)*1024 + kb);
      uint4 bv2 = *(const uint4*)(sW + (2*16 + il)*1024 + kb);
      uint4 bv3 = *(const uint4*)(sW + (3*16 + il)*1024 + kb);
      a0 = mfma16(av, bv0, a0);
      a1 = mfma16(av, bv1, a1);
      a2 = mfma16(av, bv2, a2);
      a3 = mfma16(av, bv3, a3);
    }
#pragma unroll
    for (int k = 0; k < 16; ++k) ga[k] = gb[k];   // rotate Gin buffers

    // lane-local gates (i=a0, f=a1, g=a2, o=a3); D row=(lane>>4)*4+r = batch, col=il = dim
    float hr[4];
#pragma unroll
    for (int r = 0; r < 4; ++r) {
      float cv = sigf(a1[r])*cst[r] + sigf(a0[r])*tanhf_fast(a2[r]);
      hr[r] = sigf(a3[r])*tanhf_fast(cv);
      cst[r] = cv;
    }
    // pair dims (d, d+1) across neighbor lanes; even lanes publish tagged u64 + Hhi/Hlo
#pragma unroll
    for (int r = 0; r < 4; ++r) {
      uint16_t hh = f2bf(hr[r]);
      float lo = hr[r] - bf2f(hh);
      float hn = __shfl_xor(hr[r], 1);
      float ln = __shfl_xor(lo, 1);
      if ((lane & 1) == 0) {
        uint32_t pay = (uint32_t)hh | ((uint32_t)f2bf(hn) << 16);
        uint32_t lop = (uint32_t)f2bf(lo) | ((uint32_t)f2bf(ln) << 16);
        int bp = kq*4 + r;
        int n = (s*8 + (il >> 1))*16 + bp;
        __hip_atomic_store(Tg + (size_t)((t + 1) & 1)*8192 + (size_t)m*4096 + n,
            ((unsigned long long)(uint32_t)(t + 1) << 32) | (unsigned long long)pay,
            __ATOMIC_RELAXED, __HIP_MEMORY_SCOPE_AGENT);
        size_t hoff = ((size_t)(m*16 + bp)*SEQ + t)*NHID + d;   // b-major; d even
        *(uint32_t*)(Hhi + hoff) = pay;
        *(uint32_t*)(Hlo + hoff) = lop;
      }
    }
    if (t == SEQ-1) {
#pragma unroll
      for (int r = 0; r < 4; ++r) {
        outT[(bbase + r)*NHID + d] = hr[r];
        outT[BS*NHID + (bbase + r)*NHID + d] = cst[r];
      }
    }
    // no barrier anywhere: next step's tag validation IS the synchronization
  }
}

// ---------------- decode (standalone): 4-operand fused k-loop, 2 blocks/CU, XCD swizzle ----------
__global__ __launch_bounds__(256) void decode_kernel(
    const char* __restrict__ ws, const float* __restrict__ bdec,
    float* __restrict__ out) {
  __shared__ __align__(16) char lds[2][32768];
  const uint16_t* Hhi = (const uint16_t*)(ws + WS_HHI);
  const uint16_t* Hlo = (const uint16_t*)(ws + WS_HLO);
  const uint16_t* WDH = (const uint16_t*)(ws + WS_WDH);
  const uint16_t* WDL = (const uint16_t*)(ws + WS_WDL);
  const int tid = threadIdx.x;
  const int lane = tid & 63, w = tid >> 6;
  const int wbase = (tid & ~63);
  const int mq = (w >> 1) * 64, nq = (w & 1) * 64;
  const int bid = (int)blockIdx.x;
  const int swz = (bid & 7) * (NTILE / 8) + (bid >> 3);
  const int mt = swz / 40, nt = swz % 40;
  const int m0 = mt * 128, n0 = nt * 128;

  auto stage = [&](int buf, int kk) {
    char* base = &lds[buf][0];
#pragma unroll
    for (int c2 = 0; c2 < 2; ++c2) {
      int idx = c2*256 + tid;
      int row = idx >> 2, col = (idx & 3) * 8;
      int ldst = (c2*256 + wbase) * 16;
      glds16(Hhi + (size_t)(m0 + row) * NHID + kk*32 + col, base + ldst);
      glds16(Hlo + (size_t)(m0 + row) * NHID + kk*32 + col, base + 8192 + ldst);
      glds16(WDH + (size_t)(n0 + row) * NHID + kk*32 + col, base + 16384 + ldst);
      glds16(WDL + (size_t)(n0 + row) * NHID + kk*32 + col, base + 24576 + ldst);
    }
  };

  const f32x4 zero = {0.f, 0.f, 0.f, 0.f};
  f32x4 acc[4][4];
#pragma unroll
  for (int i = 0; i < 4; ++i)
#pragma unroll
    for (int j = 0; j < 4; ++j) acc[i][j] = zero;

  stage(0, 0);
  for (int s = 0; s < 16; ++s) {
    __syncthreads();
    if (s + 1 < 16) stage((s + 1) & 1, s + 1);
    const char* cb = &lds[s & 1][0];
    uint4 ahi[4], alo[4], bhi[4], blo[4];
#pragma unroll
    for (int i = 0; i < 4; ++i) {
      int aoff = (mq + i*16 + (lane & 15))*64 + (lane >> 4)*16;
      int boff = (nq + i*16 + (lane & 15))*64 + (lane >> 4)*16;
      ahi[i] = *(const uint4*)(cb + aoff);
      alo[i] = *(const uint4*)(cb + 8192 + aoff);
      bhi[i] = *(const uint4*)(cb + 16384 + boff);
      blo[i] = *(const uint4*)(cb + 24576 + boff);
    }
#pragma unroll
    for (int i = 0; i < 4; ++i)
#pragma unroll
      for (int j = 0; j < 4; ++j) {
        acc[i][j] = mfma16(ahi[i], bhi[j], acc[i][j]);
        acc[i][j] = mfma16(ahi[i], blo[j], acc[i][j]);
        acc[i][j] = mfma16(alo[i], bhi[j], acc[i][j]);
      }
  }
  // epilogue: b-major H rows ARE output rows (b*512+t)
#pragma unroll
  for (int j = 0; j < 4; ++j) {
    int V = n0 + nq + j*16 + (lane & 15);
    if (V >= VOCAB) continue;
    float bv = bdec[V];
#pragma unroll
    for (int i = 0; i < 4; ++i) {
      int Rb = m0 + mq + i*16 + (lane >> 4)*4;
#pragma unroll
      for (int r = 0; r < 4; ++r)
        out[(size_t)(Rb + r) * VOCAB + V] = acc[i][j][r] + bv;
    }
  }
}

extern "C" void kernel_launch(void* const* d_in, const int* in_sizes, int n_in,
                              void* d_out, int out_size, void* d_ws, size_t ws_size,
                              hipStream_t stream) {
  (void)in_sizes; (void)n_in; (void)out_size; (void)ws_size;
  const int*   inputs = (const int*)  d_in[0];
  const float* h0     = (const float*)d_in[1];
  const float* c0     = (const float*)d_in[2];
  // d_in[3] measure_weights, d_in[4] measure_steps, d_in[12] measure_length: dead (GAMMA==0)
  const float* emb    = (const float*)d_in[5];
  const float* Wih    = (const float*)d_in[6];
  const float* Whh    = (const float*)d_in[7];
  const float* bih    = (const float*)d_in[8];
  const float* bhh    = (const float*)d_in[9];
  const float* Wdec   = (const float*)d_in[10];
  const float* bdec   = (const float*)d_in[11];
  char* ws   = (char*)d_ws;
  float* out = (float*)d_out;
  float* Gin  = out;                          // f32[16384][2048] scratch inside dec region,
                                              // fully consumed by scan before decode overwrites
  float* outT = out + (size_t)BS*SEQ*VOCAB;   // hT then cT

  prep_kernel<<<512, 256, 0, stream>>>(inputs, h0, emb, Wih, Whh, bih, bhh, Wdec, ws);
  // G_in = X @ W_ih^T + (b_ih+b_hh); rows r = t*32+b
  gemm_kernel<8,1><<<dim3(GH/128, (BS*SEQ)/128), 256, 0, stream>>>(
      (const uint16_t*)(ws + WS_X), (const uint16_t*)(ws + WS_WIH),
      (const float*)(ws + WS_BIAS), Gin, GH, GH);
  scan_kernel<<<64, 64, 0, stream>>>(Gin, ws, c0, outT);
  decode_kernel<<<NTILE, 256, 0, stream>>>(ws, bdec, out);
}

// Round 16
// 1837.575 us; speedup vs baseline: 1.5634x; 1.5634x over previous
//
#include <hip/hip_runtime.h>
#include <cstdint>
#include <cstddef>

// Problem constants (reference: BS,SEQ,VOCAB,EMS,NHID,ML = 32,512,5000,256,512,16)
#define BS     32
#define SEQ    512
#define VOCAB  5000
#define EMS    256
#define NHID   512
#define GH     2048        // 4*NHID gate rows
#define NWG    32          // scan workgroups (one 16-dim hidden slice each)
#define SLICE  16          // NHID / NWG
#define VPAD   5120        // VOCAB padded to 128
#define NTILE  ((BS*SEQ/128) * (VPAD/128))   // 128 x 40 = 5120 decode tiles

// ---- workspace layout (bytes); ~55.7 MB ----
#define WS_FLAGS 0                                 // u32[32] @64B stride (2 KB)
#define WS_BIAS  2048                              // f32[2048]  (b_ih+b_hh)
#define WS_WIH   (WS_BIAS + GH*4)                  // bf16[2048][256]
#define WS_WHH   (WS_WIH + GH*EMS*2)               // bf16[2048][512]
#define WS_WDH   (WS_WHH + GH*NHID*2)              // bf16[5120][512] W_dec hi
#define WS_WDL   (WS_WDH + VPAD*NHID*2)            // bf16[5120][512] W_dec lo
#define WS_X     (WS_WDL + VPAD*NHID*2)            // bf16[512][32][256] emb gather (t-major)
#define WS_HHI   (WS_X + SEQ*BS*EMS*2)             // bf16[32*512][512] h hi (b-major rows b*512+t)
#define WS_HLO   (WS_HHI + BS*SEQ*NHID*2)          // bf16[32*512][512] h lo (b-major)
#define WS_HBUF  (WS_HLO + BS*SEQ*NHID*2)          // bf16[2][32][512] h exchange (parity dbuf)
#define WS_END   (WS_HBUF + 2*BS*NHID*2)

typedef float f32x4 __attribute__((ext_vector_type(4)));
typedef __bf16 bf16x8 __attribute__((ext_vector_type(8)));

static __device__ __forceinline__ uint16_t f2bf(float x) {
  uint32_t u = __builtin_bit_cast(uint32_t, x);
  u += 0x7FFFu + ((u >> 16) & 1u);        // RNE (inputs finite)
  return (uint16_t)(u >> 16);
}
static __device__ __forceinline__ float bf2f(uint16_t b) {
  return __builtin_bit_cast(float, (uint32_t)b << 16);
}
static __device__ __forceinline__ float sigf(float x) { return 1.0f / (1.0f + __expf(-x)); }
static __device__ __forceinline__ float tanhf_fast(float x) {
  return 1.0f - 2.0f / (__expf(2.0f * x) + 1.0f);
}
static __device__ __forceinline__ f32x4 mfma16(uint4 a, uint4 b, f32x4 c) {
  return __builtin_amdgcn_mfma_f32_16x16x32_bf16(
      __builtin_bit_cast(bf16x8, a), __builtin_bit_cast(bf16x8, b), c, 0, 0, 0);
}
// async global->LDS, 16B/lane; LDS dest = wave-uniform base + lane*16 (m104)
static __device__ __forceinline__ void glds16(const void* g, void* l) {
  __builtin_amdgcn_global_load_lds((__attribute__((address_space(1))) void*)g,
                                   (__attribute__((address_space(3))) void*)l,
                                   16, 0, 0);
}
// agent-scope coherent (LLC) store — write-through, no fence needed
static __device__ __forceinline__ void coh_store_u32(uint32_t* p, uint32_t v) {
  __hip_atomic_store(p, v, __ATOMIC_RELAXED, __HIP_MEMORY_SCOPE_AGENT);
}

// ---------------- prep: bf16 casts, emb gather, W_dec hi/lo split, bias, h0, flags ----------------
__global__ __launch_bounds__(256) void prep_kernel(
    const int* __restrict__ inputs, const float* __restrict__ h0,
    const float* __restrict__ emb, const float* __restrict__ Wih,
    const float* __restrict__ Whh, const float* __restrict__ bih,
    const float* __restrict__ bhh, const float* __restrict__ Wd,
    char* __restrict__ ws) {
  int gid = blockIdx.x * 256 + threadIdx.x;
  int gsz = gridDim.x * 256;
  uint16_t* wX  = (uint16_t*)(ws + WS_X);
  uint16_t* wIH = (uint16_t*)(ws + WS_WIH);
  uint16_t* wHH = (uint16_t*)(ws + WS_WHH);
  uint16_t* wDH = (uint16_t*)(ws + WS_WDH);
  uint16_t* wDL = (uint16_t*)(ws + WS_WDL);
  float*    bias = (float*)(ws + WS_BIAS);
  uint16_t* hb  = (uint16_t*)(ws + WS_HBUF);
  if (gid < 512) ((uint32_t*)(ws + WS_FLAGS))[gid] = 0u;   // flags reset each launch
  // X[t][b][e] = bf16(emb[inputs[b][t]][e]);  i = t*8192 + b*256 + e
  for (int i = gid; i < SEQ*BS*EMS; i += gsz) {
    int e = i & (EMS-1), b = (i >> 8) & (BS-1), t = i >> 13;
    wX[i] = f2bf(emb[(size_t)inputs[b*SEQ + t] * EMS + e]);
  }
  for (int i = gid; i < GH*EMS; i += gsz)  wIH[i] = f2bf(Wih[i]);
  for (int i = gid; i < GH*NHID; i += gsz) wHH[i] = f2bf(Whh[i]);
  for (int i = gid; i < VPAD*NHID; i += gsz) {   // hi/lo split; pad rows >= VOCAB with 0
    int row = i >> 9;
    uint16_t hi = 0, lo = 0;
    if (row < VOCAB) {
      float x = Wd[i];
      hi = f2bf(x);
      lo = f2bf(x - bf2f(hi));
    }
    wDH[i] = hi; wDL[i] = lo;
  }
  for (int i = gid; i < GH; i += gsz) bias[i] = bih[i] + bhh[i];
  for (int i = gid; i < BS*NHID; i += gsz) hb[i] = f2bf(h0[i]);   // parity-0 h buffer
}

// ---------------- generic 128x128 MFMA GEMM (m97-style) — used for Gin only ----------------
template <int KSTEPS, int NPASS>
__global__ __launch_bounds__(256) void gemm_kernel(
    const uint16_t* __restrict__ A0, const uint16_t* __restrict__ B0,
    const float* __restrict__ bias, float* __restrict__ out,
    int Nvalid, int ldout) {
  constexpr int K = KSTEPS * 32;
  constexpr int TOT = KSTEPS * NPASS;
  __shared__ __align__(16) char lds[4][8192];
  const int tid = threadIdx.x;
  const int lane = tid & 63, w = tid >> 6;
  const int m0 = blockIdx.y * 128, n0 = blockIdx.x * 128;
  const int wbase = (tid & ~63);

  auto stage = [&](int buf, int s) {
    const int kk = s % KSTEPS;
    char* dA = &lds[buf*2][0];
    char* dB = &lds[buf*2+1][0];
#pragma unroll
    for (int c = 0; c < 2; ++c) {
      int idx = c*256 + tid;
      int row = idx >> 2, col = (idx & 3) * 8;
      glds16(A0 + (size_t)(m0 + row) * K + kk*32 + col, dA + (c*256 + wbase)*16);
      glds16(B0 + (size_t)(n0 + row) * K + kk*32 + col, dB + (c*256 + wbase)*16);
    }
  };

  const f32x4 zero = {0.f, 0.f, 0.f, 0.f};
  f32x4 acc[4][4];
#pragma unroll
  for (int i = 0; i < 4; ++i)
#pragma unroll
    for (int j = 0; j < 4; ++j) acc[i][j] = zero;

  const int mq = (w >> 1) * 64, nq = (w & 1) * 64;
  stage(0, 0);
  for (int s = 0; s < TOT; ++s) {
    __syncthreads();
    if (s + 1 < TOT) stage((s + 1) & 1, s + 1);
    const char* cA = &lds[(s & 1)*2][0];
    const char* cB = &lds[(s & 1)*2+1][0];
    uint4 a[4], b[4];
#pragma unroll
    for (int i = 0; i < 4; ++i) {
      a[i] = *(const uint4*)(cA + (mq + i*16 + (lane & 15))*64 + (lane >> 4)*16);
      b[i] = *(const uint4*)(cB + (nq + i*16 + (lane & 15))*64 + (lane >> 4)*16);
    }
#pragma unroll
    for (int i = 0; i < 4; ++i)
#pragma unroll
      for (int j = 0; j < 4; ++j) acc[i][j] = mfma16(a[i], b[j], acc[i][j]);
  }
#pragma unroll
  for (int j = 0; j < 4; ++j) {
    int V = n0 + nq + j*16 + (lane & 15);
    if (V >= Nvalid) continue;
    float bv = bias[V];
#pragma unroll
    for (int i = 0; i < 4; ++i) {
      int Rb = m0 + mq + i*16 + (lane >> 4)*4;
#pragma unroll
      for (int r = 0; r < 4; ++r)
        out[(size_t)(Rb + r) * ldout + V] = acc[i][j][r] + bv;
    }
  }
}

// ---------------- LSTM scan: R4 protocol (measured best of six), post-flag H stores ----------------
// Per step: poll 32 per-WG flags -> coalesced sc0sc1 h staging (8x dwordx4, one vmcnt,
// conflict-free swizzled LDS writes) -> MFMA (Gin reg-dbuf seeds) -> sG gate exchange ->
// gates -> publish h(t+1) write-through to parity dbuf -> barrier (drains publishes) ->
// tid0 flag. Hhi/Hlo/outT stores AFTER the flag (off critical path; kernel-boundary flush).
__global__ __launch_bounds__(256, 1) void scan_kernel(
    const float* __restrict__ Gin, char* __restrict__ ws,
    const float* __restrict__ c0, float* __restrict__ outT) {
  __shared__ __align__(16) char sW[64*1024];   // W_hh slice [64 rows][512] bf16, XOR-swizzled
  __shared__ __align__(16) char sH[32*1024];   // h [32][512] bf16, XOR-swizzled
  __shared__ float sG[4*BS*SLICE];             // gates f32 [4][32][16]
  const uint16_t* wHH = (const uint16_t*)(ws + WS_WHH);
  uint16_t* hbuf = (uint16_t*)(ws + WS_HBUF);
  uint16_t* Hhi  = (uint16_t*)(ws + WS_HHI);
  uint16_t* Hlo  = (uint16_t*)(ws + WS_HLO);
  uint32_t* flags = (uint32_t*)(ws + WS_FLAGS);
  const int tid = threadIdx.x, wg = blockIdx.x;
  const int lane = tid & 63, w = tid >> 6;
  const int mw = w >> 1, nw = w & 1;           // wave: m-half (16 batches) x 2 gate-tiles

  // stage W_hh slice once: LDS row = gate*16 + dl <-> global row gate*512 + wg*16 + dl
  for (int c = tid; c < 4096; c += 256) {
    int row = c >> 6;
    int kb = (c & 63) * 16;
    int G = row >> 4, dl = row & 15;
    uint4 v = *(const uint4*)(wHH + (size_t)(G*NHID + wg*SLICE + dl) * NHID + kb/2);
    *(uint4*)(sW + row*1024 + (kb ^ ((row & 7) << 4))) = v;
  }
  const int bq = tid >> 3, dq = (tid & 7) * 2;  // this thread owns (batch bq, dims dq,dq+1)
  float c_0 = c0[bq*NHID + wg*SLICE + dq];
  float c_1 = c0[bq*NHID + wg*SLICE + dq + 1];
  const int arow = mw*16 + (lane & 15);
  const int brow0 = (2*nw)*16 + (lane & 15);
  const int brow1 = brow0 + 16;
  const int kb0 = (lane >> 4) * 16;

  // Gin double-buffer: ga = step t (consumed this step), gb = step t+1 (prefetch)
  float ga0[4], ga1[4], gb0[4], gb1[4];
  {
    const float* grow = Gin + wg*SLICE + (lane & 15);
#pragma unroll
    for (int r = 0; r < 4; ++r) {
      int b = mw*16 + (lane >> 4)*4 + r;
      ga0[r] = grow[(size_t)b*GH + (2*nw+0)*NHID];
      ga1[r] = grow[(size_t)b*GH + (2*nw+1)*NHID];
    }
  }
  __syncthreads();

  for (int t = 0; t < SEQ; ++t) {
    // P: poll 32 per-WG flags (lanes pair up on the 32 flags)
    if (t > 0) {
      const uint32_t tgt = (uint32_t)t;
      const uint32_t* fp = flags + (lane & 31) * 16;
      uint32_t ptries = 0;
      for (;;) {
        uint32_t v = __hip_atomic_load(fp, __ATOMIC_RELAXED, __HIP_MEMORY_SCOPE_AGENT);
        if (__all((int)(v >= tgt))) break;
        if (++ptries > (1u << 20)) break;   // safety: wrong-result beats timeout
      }
    }

    // A1: issue Gin(t+1) prefetch (plain cached loads; drained by the staging vmcnt)
    if (t + 1 < SEQ) {
      const float* grow = Gin + (size_t)(t+1)*(BS*GH) + wg*SLICE + (lane & 15);
#pragma unroll
      for (int r = 0; r < 4; ++r) {
        int b = mw*16 + (lane >> 4)*4 + r;
        gb0[r] = grow[(size_t)b*GH + (2*nw+0)*NHID];
        gb1[r] = grow[(size_t)b*GH + (2*nw+1)*NHID];
      }
    }

    // A2: stage h(t) — per-instruction coalesced sc0sc1 loads (round j: wave reads 1 KB
    // contiguous at j*4096 + tid*16), one vmcnt, conflict-free swizzled LDS writes.
    {
      const char* hsrc = (const char*)(hbuf + (t & 1) * (BS*NHID));
      const char* pb = hsrc + tid * 16;
      uint4 v0, v1, v2, v3, v4, v5, v6, v7;
      asm volatile("global_load_dwordx4 %0, %1, off sc0 sc1" : "=v"(v0) : "v"(pb));
      asm volatile("global_load_dwordx4 %0, %1, off sc0 sc1" : "=v"(v1) : "v"(pb + 4096));
      asm volatile("global_load_dwordx4 %0, %1, off sc0 sc1" : "=v"(v2) : "v"(pb + 8192));
      asm volatile("global_load_dwordx4 %0, %1, off sc0 sc1" : "=v"(v3) : "v"(pb + 12288));
      asm volatile("global_load_dwordx4 %0, %1, off sc0 sc1" : "=v"(v4) : "v"(pb + 16384));
      asm volatile("global_load_dwordx4 %0, %1, off sc0 sc1" : "=v"(v5) : "v"(pb + 20480));
      asm volatile("global_load_dwordx4 %0, %1, off sc0 sc1" : "=v"(v6) : "v"(pb + 24576));
      asm volatile("global_load_dwordx4 %0, %1, off sc0 sc1" : "=v"(v7) : "v"(pb + 28672));
      asm volatile("s_waitcnt vmcnt(0)" ::: "memory");
      __builtin_amdgcn_sched_barrier(0);
      const int kb = (tid & 63) * 16;
      const int ww = tid >> 6;
#define STW(J, VJ) *(uint4*)(sH + ((J)*4 + ww)*1024 + (kb ^ ((((J)&1)*4 + ww) << 4))) = VJ;
      STW(0, v0) STW(1, v1) STW(2, v2) STW(3, v3)
      STW(4, v4) STW(5, v5) STW(6, v6) STW(7, v7)
#undef STW
    }
    __syncthreads();

    // B: h @ W_hh^T (acc seeded from prefetched Gin)
    f32x4 acc0, acc1;
#pragma unroll
    for (int r = 0; r < 4; ++r) { acc0[r] = ga0[r]; acc1[r] = ga1[r]; }
#pragma unroll
    for (int kt = 0; kt < 16; ++kt) {
      int kb = kt*64 + kb0;
      uint4 av = *(const uint4*)(sH + arow*1024 + (kb ^ ((arow & 7) << 4)));
      uint4 b0 = *(const uint4*)(sW + brow0*1024 + (kb ^ ((brow0 & 7) << 4)));
      uint4 b1 = *(const uint4*)(sW + brow1*1024 + (kb ^ ((brow1 & 7) << 4)));
      acc0 = mfma16(av, b0, acc0);
      acc1 = mfma16(av, b1, acc1);
    }
#pragma unroll
    for (int r = 0; r < 4; ++r) {
      int b = mw*16 + (lane >> 4)*4 + r;
      sG[((2*nw+0)*BS + b)*SLICE + (lane & 15)] = acc0[r];
      sG[((2*nw+1)*BS + b)*SLICE + (lane & 15)] = acc1[r];
    }
    // rotate Gin buffers for next step
#pragma unroll
    for (int r = 0; r < 4; ++r) { ga0[r] = gb0[r]; ga1[r] = gb1[r]; }
    __syncthreads();

    // D: gate combine (fp32 state in registers)
    float gi0 = sG[(0*BS + bq)*SLICE + dq], gi1 = sG[(0*BS + bq)*SLICE + dq + 1];
    float gf0 = sG[(1*BS + bq)*SLICE + dq], gf1 = sG[(1*BS + bq)*SLICE + dq + 1];
    float gg0 = sG[(2*BS + bq)*SLICE + dq], gg1 = sG[(2*BS + bq)*SLICE + dq + 1];
    float go0 = sG[(3*BS + bq)*SLICE + dq], go1 = sG[(3*BS + bq)*SLICE + dq + 1];
    c_0 = sigf(gf0)*c_0 + sigf(gi0)*tanhf_fast(gg0);
    c_1 = sigf(gf1)*c_1 + sigf(gi1)*tanhf_fast(gg1);
    float h_0 = sigf(go0)*tanhf_fast(c_0);
    float h_1 = sigf(go1)*tanhf_fast(c_1);

    // E: publish h(t+1) write-through to parity dbuf (the ONLY store the barrier must drain)
    uint16_t hh0 = f2bf(h_0), hh1 = f2bf(h_1);
    uint32_t hp = (uint32_t)hh0 | ((uint32_t)hh1 << 16);
    coh_store_u32((uint32_t*)(hbuf + ((t+1) & 1)*(BS*NHID)) +
                      ((bq*NHID + wg*SLICE + dq) >> 1), hp);

    // F: barrier drains publishes (acked at LLC), then tid0 flag
    __syncthreads();
    if (tid == 0)
      __hip_atomic_store(flags + wg * 16, (uint32_t)(t + 1),
                         __ATOMIC_RELAXED, __HIP_MEMORY_SCOPE_AGENT);

    // G: off-critical-path stores (consumed only after kernel end; boundary flush)
    size_t hoff = ((size_t)bq*SEQ + t)*NHID + wg*SLICE + dq;   // b-major rows b*512+t
    *(uint32_t*)(Hhi + hoff) = hp;
    uint32_t lp = (uint32_t)f2bf(h_0 - bf2f(hh0)) | ((uint32_t)f2bf(h_1 - bf2f(hh1)) << 16);
    *(uint32_t*)(Hlo + hoff) = lp;
    if (t == SEQ-1) {
      outT[bq*NHID + wg*SLICE + dq]     = h_0;
      outT[bq*NHID + wg*SLICE + dq + 1] = h_1;
      outT[BS*NHID + bq*NHID + wg*SLICE + dq]     = c_0;
      outT[BS*NHID + bq*NHID + wg*SLICE + dq + 1] = c_1;
    }
  }
}

// ---------------- decode (standalone): 4-operand fused k-loop, 2 blocks/CU, XCD swizzle ----------
// acc = Ahi@Bhi + Ahi@Blo + Alo@Bhi per k-step; {Ahi,Alo,Bhi,Blo} staged once (32 KB, dbuf).
__global__ __launch_bounds__(256) void decode_kernel(
    const char* __restrict__ ws, const float* __restrict__ bdec,
    float* __restrict__ out) {
  __shared__ __align__(16) char lds[2][32768];
  const uint16_t* Hhi = (const uint16_t*)(ws + WS_HHI);
  const uint16_t* Hlo = (const uint16_t*)(ws + WS_HLO);
  const uint16_t* WDH = (const uint16_t*)(ws + WS_WDH);
  const uint16_t* WDL = (const uint16_t*)(ws + WS_WDL);
  const int tid = threadIdx.x;
  const int lane = tid & 63, w = tid >> 6;
  const int wbase = (tid & ~63);
  const int mq = (w >> 1) * 64, nq = (w & 1) * 64;
  // XCD-aware swizzle (NTILE % 8 == 0): contiguous q-chunk per XCD -> A/B panel L2 reuse
  const int bid = (int)blockIdx.x;
  const int swz = (bid & 7) * (NTILE / 8) + (bid >> 3);
  const int mt = swz / 40, nt = swz % 40;
  const int m0 = mt * 128, n0 = nt * 128;

  auto stage = [&](int buf, int kk) {
    char* base = &lds[buf][0];
#pragma unroll
    for (int c2 = 0; c2 < 2; ++c2) {
      int idx = c2*256 + tid;
      int row = idx >> 2, col = (idx & 3) * 8;
      int ldst = (c2*256 + wbase) * 16;
      glds16(Hhi + (size_t)(m0 + row) * NHID + kk*32 + col, base + ldst);
      glds16(Hlo + (size_t)(m0 + row) * NHID + kk*32 + col, base + 8192 + ldst);
      glds16(WDH + (size_t)(n0 + row) * NHID + kk*32 + col, base + 16384 + ldst);
      glds16(WDL + (size_t)(n0 + row) * NHID + kk*32 + col, base + 24576 + ldst);
    }
  };

  const f32x4 zero = {0.f, 0.f, 0.f, 0.f};
  f32x4 acc[4][4];
#pragma unroll
  for (int i = 0; i < 4; ++i)
#pragma unroll
    for (int j = 0; j < 4; ++j) acc[i][j] = zero;

  stage(0, 0);
  for (int s = 0; s < 16; ++s) {
    __syncthreads();
    if (s + 1 < 16) stage((s + 1) & 1, s + 1);
    const char* cb = &lds[s & 1][0];
    uint4 ahi[4], alo[4], bhi[4], blo[4];
#pragma unroll
    for (int i = 0; i < 4; ++i) {
      int aoff = (mq + i*16 + (lane & 15))*64 + (lane >> 4)*16;
      int boff = (nq + i*16 + (lane & 15))*64 + (lane >> 4)*16;
      ahi[i] = *(const uint4*)(cb + aoff);
      alo[i] = *(const uint4*)(cb + 8192 + aoff);
      bhi[i] = *(const uint4*)(cb + 16384 + boff);
      blo[i] = *(const uint4*)(cb + 24576 + boff);
    }
#pragma unroll
    for (int i = 0; i < 4; ++i)
#pragma unroll
      for (int j = 0; j < 4; ++j) {
        acc[i][j] = mfma16(ahi[i], bhi[j], acc[i][j]);
        acc[i][j] = mfma16(ahi[i], blo[j], acc[i][j]);
        acc[i][j] = mfma16(alo[i], bhi[j], acc[i][j]);
      }
  }
  // epilogue: b-major H rows ARE output rows (b*512+t)
#pragma unroll
  for (int j = 0; j < 4; ++j) {
    int V = n0 + nq + j*16 + (lane & 15);
    if (V >= VOCAB) continue;
    float bv = bdec[V];
#pragma unroll
    for (int i = 0; i < 4; ++i) {
      int Rb = m0 + mq + i*16 + (lane >> 4)*4;
#pragma unroll
      for (int r = 0; r < 4; ++r)
        out[(size_t)(Rb + r) * VOCAB + V] = acc[i][j][r] + bv;
    }
  }
}

extern "C" void kernel_launch(void* const* d_in, const int* in_sizes, int n_in,
                              void* d_out, int out_size, void* d_ws, size_t ws_size,
                              hipStream_t stream) {
  (void)in_sizes; (void)n_in; (void)out_size; (void)ws_size;
  const int*   inputs = (const int*)  d_in[0];
  const float* h0     = (const float*)d_in[1];
  const float* c0     = (const float*)d_in[2];
  // d_in[3] measure_weights, d_in[4] measure_steps, d_in[12] measure_length: dead (GAMMA==0)
  const float* emb    = (const float*)d_in[5];
  const float* Wih    = (const float*)d_in[6];
  const float* Whh    = (const float*)d_in[7];
  const float* bih    = (const float*)d_in[8];
  const float* bhh    = (const float*)d_in[9];
  const float* Wdec   = (const float*)d_in[10];
  const float* bdec   = (const float*)d_in[11];
  char* ws   = (char*)d_ws;
  float* out = (float*)d_out;
  float* Gin  = out;                          // f32[16384][2048] scratch inside dec region,
                                              // fully consumed by scan before decode overwrites
  float* outT = out + (size_t)BS*SEQ*VOCAB;   // hT then cT

  prep_kernel<<<512, 256, 0, stream>>>(inputs, h0, emb, Wih, Whh, bih, bhh, Wdec, ws);
  // G_in = X @ W_ih^T + (b_ih+b_hh); rows r = t*32+b
  gemm_kernel<8,1><<<dim3(GH/128, (BS*SEQ)/128), 256, 0, stream>>>(
      (const uint16_t*)(ws + WS_X), (const uint16_t*)(ws + WS_WIH),
      (const float*)(ws + WS_BIAS), Gin, GH, GH);
  scan_kernel<<<NWG, 256, 0, stream>>>(Gin, ws, c0, outT);
  decode_kernel<<<NTILE, 256, 0, stream>>>(ws, bdec, out);
}